// Round 1
// baseline (395.522 us; speedup 1.0000x reference)
//
#include <hip/hip_runtime.h>

// Problem: AverageTreatmentEffectLoss — reduce out/sensitive/y [N] to one f32.
// X (d_in[0]) is unused by the reference; we never touch it (saves 256 MB).
// Roofline: 96 MB read @ ~6.3 TB/s => ~15.3 us.

#define BLOCK 256
#define GRID 2048

__global__ __launch_bounds__(BLOCK) void atel_count_kernel(
    const float* __restrict__ out,
    const int*   __restrict__ sens,
    const int*   __restrict__ y,
    unsigned long long* __restrict__ ws,
    int n4)
{
    const float4* __restrict__ out4 = (const float4*)out;
    const int4*   __restrict__ s4   = (const int4*)sens;
    const int4*   __restrict__ y4   = (const int4*)y;

    unsigned int tp_p = 0, fn_p = 0, tp_n = 0, fn_n = 0;

    int idx    = blockIdx.x * BLOCK + threadIdx.x;
    int stride = gridDim.x * BLOCK;

    for (int i = idx; i < n4; i += stride) {
        float4 o  = out4[i];
        int4   s  = s4[i];
        int4   yy = y4[i];

        float ov[4] = {o.x, o.y, o.z, o.w};
        int   sv[4] = {s.x, s.y, s.z, s.w};
        int   yv[4] = {yy.x, yy.y, yy.z, yy.w};

        #pragma unroll
        for (int j = 0; j < 4; ++j) {
            // faithful sigmoid; equality vs float(y) can only flip if p hits
            // exactly 0.0/1.0, which needs |out| > 17 — ulp error irrelevant.
            float p = 1.0f / (1.0f + __expf(-ov[j]));
            bool pos  = (yv[j] == 1);
            if (pos) {
                bool prot = (sv[j] == 0);
                bool eq   = ((float)yv[j] == p);
                if (prot) {
                    if (eq) tp_p++; else fn_p++;
                } else {
                    if (eq) tp_n++; else fn_n++;
                }
            }
        }
    }

    // pack: low32 = tp, high32 = fn (block-level sums < 2^16, global < 2^32)
    unsigned long long a = ((unsigned long long)fn_p << 32) | (unsigned long long)tp_p;
    unsigned long long b = ((unsigned long long)fn_n << 32) | (unsigned long long)tp_n;

    // wave64 reduction
    #pragma unroll
    for (int off = 32; off > 0; off >>= 1) {
        a += __shfl_down(a, off, 64);
        b += __shfl_down(b, off, 64);
    }

    __shared__ unsigned long long red[2][BLOCK / 64];
    int wave = threadIdx.x >> 6;
    int lane = threadIdx.x & 63;
    if (lane == 0) { red[0][wave] = a; red[1][wave] = b; }
    __syncthreads();
    if (threadIdx.x == 0) {
        unsigned long long A = 0, B = 0;
        #pragma unroll
        for (int w = 0; w < BLOCK / 64; ++w) { A += red[0][w]; B += red[1][w]; }
        atomicAdd(&ws[0], A);
        atomicAdd(&ws[1], B);
    }
}

__global__ void atel_finalize_kernel(const unsigned long long* __restrict__ ws,
                                     float* __restrict__ result)
{
    unsigned long long A = ws[0], B = ws[1];
    float tp_p = (float)(unsigned int)(A & 0xffffffffULL);
    float fn_p = (float)(unsigned int)(A >> 32);
    float tp_n = (float)(unsigned int)(B & 0xffffffffULL);
    float fn_n = (float)(unsigned int)(B >> 32);

    float dp = tp_p + fn_p;
    float tpr_p = (dp == 0.0f) ? 0.0f : tp_p / fmaxf(dp, 1.0f);
    float dn = tp_n + fn_n;
    float tpr_n = (dn == 0.0f) ? 0.0f : tp_n / fmaxf(dn, 1.0f);

    // M@mu = [d, -d, d, -d], d = tpr_n - tpr_p; gap=relu; alpha*dot(gap,gap)
    float d  = tpr_n - tpr_p;
    float g1 = fmaxf(d, 0.0f);
    float g2 = fmaxf(-d, 0.0f);
    result[0] = 2.0f * (g1 * g1 + g2 * g2);
}

extern "C" void kernel_launch(void* const* d_in, const int* in_sizes, int n_in,
                              void* d_out, int out_size, void* d_ws, size_t ws_size,
                              hipStream_t stream) {
    // d_in[0] = X [N,8] f32 (UNUSED), d_in[1] = out [N] f32,
    // d_in[2] = sensitive [N] i32, d_in[3] = y [N] i32
    const float* out  = (const float*)d_in[1];
    const int*   sens = (const int*)d_in[2];
    const int*   y    = (const int*)d_in[3];
    int n = in_sizes[1];

    unsigned long long* ws = (unsigned long long*)d_ws;

    hipMemsetAsync(d_ws, 0, 2 * sizeof(unsigned long long), stream);
    atel_count_kernel<<<GRID, BLOCK, 0, stream>>>(out, sens, y, ws, n / 4);
    atel_finalize_kernel<<<1, 1, 0, stream>>>(ws, (float*)d_out);
}

// Round 2
// 357.129 us; speedup vs baseline: 1.1075x; 1.1075x over previous
//
#include <hip/hip_runtime.h>

// AverageTreatmentEffectLoss — reduce out/sensitive/y [N] to one f32 scalar.
// X (d_in[0]) is unused by the reference; never touched (saves 256 MB).
// Controllable roofline: 96 MB read @ ~6.7 TB/s => ~14.5 us + 2 launches.
// R2: no-atomic / no-memset scheme — each block writes its partial counts to
// a private ws slot (unconditionally, so 0xAA poison is fine); finalize
// kernel reduces the slots. Saves one graph node vs R1.

#define BLOCK 256
#define GRID  1024   // 8 float4-iters/thread at N=8388608

__global__ __launch_bounds__(BLOCK) void atel_count_kernel(
    const float* __restrict__ out,
    const int*   __restrict__ sens,
    const int*   __restrict__ y,
    unsigned long long* __restrict__ ws,   // [GRID][2]
    int n4)
{
    const float4* __restrict__ out4 = (const float4*)out;
    const int4*   __restrict__ s4   = (const int4*)sens;
    const int4*   __restrict__ y4   = (const int4*)y;

    unsigned int tp_p = 0, fn_p = 0, tp_n = 0, fn_n = 0;

    int idx    = blockIdx.x * BLOCK + threadIdx.x;
    int stride = gridDim.x * BLOCK;

    for (int i = idx; i < n4; i += stride) {
        float4 o  = out4[i];
        int4   s  = s4[i];
        int4   yy = y4[i];

        float ov[4] = {o.x, o.y, o.z, o.w};
        int   sv[4] = {s.x, s.y, s.z, s.w};
        int   yv[4] = {yy.x, yy.y, yy.z, yy.w};

        #pragma unroll
        for (int j = 0; j < 4; ++j) {
            // faithful sigmoid; (float)y == p can only be true if p is exactly
            // 0.0f/1.0f (needs |out| > ~16.6) — 1-ulp expf error irrelevant
            // elsewhere since p is strictly inside (0,1).
            float p = 1.0f / (1.0f + __expf(-ov[j]));
            if (yv[j] == 1) {
                bool prot = (sv[j] == 0);
                bool eq   = (1.0f == p);   // y==1 here, so (float)y == 1.0f
                if (prot) { if (eq) tp_p++; else fn_p++; }
                else      { if (eq) tp_n++; else fn_n++; }
            }
        }
    }

    // pack: low32 = tp, high32 = fn (global totals <= N < 2^32, no overflow)
    unsigned long long a = ((unsigned long long)fn_p << 32) | (unsigned long long)tp_p;
    unsigned long long b = ((unsigned long long)fn_n << 32) | (unsigned long long)tp_n;

    // wave64 reduction
    #pragma unroll
    for (int off = 32; off > 0; off >>= 1) {
        a += __shfl_down(a, off, 64);
        b += __shfl_down(b, off, 64);
    }

    __shared__ unsigned long long red[2][BLOCK / 64];
    int wave = threadIdx.x >> 6;
    int lane = threadIdx.x & 63;
    if (lane == 0) { red[0][wave] = a; red[1][wave] = b; }
    __syncthreads();
    if (threadIdx.x == 0) {
        unsigned long long A = 0, B = 0;
        #pragma unroll
        for (int w = 0; w < BLOCK / 64; ++w) { A += red[0][w]; B += red[1][w]; }
        // unconditional slot write — no zero-init of ws needed
        ws[2 * blockIdx.x + 0] = A;
        ws[2 * blockIdx.x + 1] = B;
    }
}

__global__ __launch_bounds__(BLOCK) void atel_finalize_kernel(
    const unsigned long long* __restrict__ ws,  // [GRID][2]
    float* __restrict__ result)
{
    unsigned long long a = 0, b = 0;
    for (int i = threadIdx.x; i < GRID; i += BLOCK) {
        a += ws[2 * i + 0];
        b += ws[2 * i + 1];
    }
    #pragma unroll
    for (int off = 32; off > 0; off >>= 1) {
        a += __shfl_down(a, off, 64);
        b += __shfl_down(b, off, 64);
    }
    __shared__ unsigned long long red[2][BLOCK / 64];
    int wave = threadIdx.x >> 6;
    int lane = threadIdx.x & 63;
    if (lane == 0) { red[0][wave] = a; red[1][wave] = b; }
    __syncthreads();
    if (threadIdx.x == 0) {
        unsigned long long A = 0, B = 0;
        #pragma unroll
        for (int w = 0; w < BLOCK / 64; ++w) { A += red[0][w]; B += red[1][w]; }

        float tp_p = (float)(unsigned int)(A & 0xffffffffULL);
        float fn_p = (float)(unsigned int)(A >> 32);
        float tp_n = (float)(unsigned int)(B & 0xffffffffULL);
        float fn_n = (float)(unsigned int)(B >> 32);

        float dp = tp_p + fn_p;
        float tpr_p = (dp == 0.0f) ? 0.0f : tp_p / fmaxf(dp, 1.0f);
        float dn = tp_n + fn_n;
        float tpr_n = (dn == 0.0f) ? 0.0f : tp_n / fmaxf(dn, 1.0f);

        // M@mu = [d, -d, d, -d], d = tpr_n - tpr_p; gap = relu; alpha*dot(gap,gap)
        float d  = tpr_n - tpr_p;
        float g1 = fmaxf(d, 0.0f);
        float g2 = fmaxf(-d, 0.0f);
        result[0] = 2.0f * (g1 * g1 + g2 * g2);
    }
}

extern "C" void kernel_launch(void* const* d_in, const int* in_sizes, int n_in,
                              void* d_out, int out_size, void* d_ws, size_t ws_size,
                              hipStream_t stream) {
    // d_in[0] = X [N,8] f32 (UNUSED), d_in[1] = out [N] f32,
    // d_in[2] = sensitive [N] i32, d_in[3] = y [N] i32
    const float* out  = (const float*)d_in[1];
    const int*   sens = (const int*)d_in[2];
    const int*   y    = (const int*)d_in[3];
    int n = in_sizes[1];

    unsigned long long* ws = (unsigned long long*)d_ws;

    atel_count_kernel<<<GRID, BLOCK, 0, stream>>>(out, sens, y, ws, n / 4);
    atel_finalize_kernel<<<1, BLOCK, 0, stream>>>(ws, (float*)d_out);
}